// Round 4
// baseline (160.034 us; speedup 1.0000x reference)
//
#include <hip/hip_runtime.h>

// GlobalFusion: scatter global rows into a dense 3D grid hash, then per local
// point gather the coarse-scale global feature row and concat with local row.
//
// scale ratio = (4,4,4) -> floor-div by 4 == arithmetic >>2
// C = 64 floats per feature row; output row = 128 floats = 32 float4.
//
// R4: R3 structure (16 threads/row, non-divergent, nt on streaming traffic),
//     single change: grid-stride loop @ 8192 blocks (guideline 11).

#define SCALE_SHIFT 2
#define C4 16            // 64 floats = 16 float4 per input row
#define OUT4 32          // 128 floats = 32 float4 per output row

typedef float f32x4 __attribute__((ext_vector_type(4)));

__global__ void build_grid_kernel(const int* __restrict__ gcoords,
                                  int n_global,
                                  const int* __restrict__ gs_ptr,
                                  int* __restrict__ grid) {
    int i = blockIdx.x * blockDim.x + threadIdx.x;
    if (i >= n_global) return;
    int gs = *gs_ptr;
    int x = gcoords[3 * i + 0];
    int y = gcoords[3 * i + 1];
    int z = gcoords[3 * i + 2];
    // reference: grid.at[flat].max(row_index) -> atomicMax resolves duplicates
    atomicMax(&grid[(x * gs + y) * gs + z], i);
}

__global__ void __launch_bounds__(256)
fuse_kernel(const f32x4* __restrict__ lf4,   // n_local  x 16
            const f32x4* __restrict__ gf4,   // n_global x 16
            const int* __restrict__ lcoords, // n_local x 3
            const int* __restrict__ lbase,   // 3
            const int* __restrict__ gbase,   // 3
            const int* __restrict__ grid,    // gs^3
            int n_local,
            const int* __restrict__ gs_ptr,
            f32x4* __restrict__ out4)        // n_local x 32
{
    const int gs = *gs_ptr;
    const int lb0 = lbase[0], lb1 = lbase[1], lb2 = lbase[2];
    const int gb0 = gbase[0], gb1 = gbase[1], gb2 = gbase[2];
    const long long total = (long long)n_local * 16;
    const long long stride = (long long)gridDim.x * blockDim.x;

    for (long long t = (long long)blockIdx.x * blockDim.x + threadIdx.x;
         t < total; t += stride) {
        int row = (int)(t >> 4);   // 16 threads per row
        int j   = (int)(t & 15);

        // local half: streaming copy (coalesced float4, single-use -> nt)
        f32x4 lv = __builtin_nontemporal_load(&lf4[(size_t)row * C4 + j]);
        __builtin_nontemporal_store(lv, &out4[(size_t)row * OUT4 + j]);

        // gathered half (grid + gf reads stay cached)
        int gx = ((lcoords[3 * row + 0] + lb0) >> SCALE_SHIFT) - gb0;
        int gy = ((lcoords[3 * row + 1] + lb1) >> SCALE_SHIFT) - gb1;
        int gz = ((lcoords[3 * row + 2] + lb2) >> SCALE_SHIFT) - gb2;
        bool inb = ((unsigned)gx < (unsigned)gs) &
                   ((unsigned)gy < (unsigned)gs) &
                   ((unsigned)gz < (unsigned)gs);
        int cx = min(max(gx, 0), gs - 1);
        int cy = min(max(gy, 0), gs - 1);
        int cz = min(max(gz, 0), gs - 1);
        int idx = grid[(cx * gs + cy) * gs + cz];

        f32x4 v = (f32x4)(0.f, 0.f, 0.f, 0.f);
        if (inb && idx >= 0) {
            v = gf4[(size_t)idx * C4 + j];
        }
        __builtin_nontemporal_store(v, &out4[(size_t)row * OUT4 + C4 + j]);
    }
}

extern "C" void kernel_launch(void* const* d_in, const int* in_sizes, int n_in,
                              void* d_out, int out_size, void* d_ws, size_t ws_size,
                              hipStream_t stream) {
    const float* lf = (const float*)d_in[0];
    const float* gf = (const float*)d_in[1];
    const int*   lc = (const int*)d_in[2];
    const int*   gc = (const int*)d_in[3];
    const int*   lb = (const int*)d_in[4];
    const int*   gb = (const int*)d_in[5];
    // d_in[6] = local_spatial_size (unused), d_in[7] = global_spatial_size
    const int*   gs_ptr = (const int*)d_in[7];

    int n_local  = in_sizes[0] / 64;
    int n_global = in_sizes[1] / 64;

    // grid hash lives in workspace: 128^3 int32 = 8 MiB, init to -1 (0xFF)
    int* grid = (int*)d_ws;
    const size_t grid_bytes = (size_t)128 * 128 * 128 * sizeof(int);
    hipMemsetAsync(d_ws, 0xFF, grid_bytes, stream);

    build_grid_kernel<<<(n_global + 255) / 256, 256, 0, stream>>>(
        gc, n_global, gs_ptr, grid);

    fuse_kernel<<<8192, 256, 0, stream>>>(
        (const f32x4*)lf, (const f32x4*)gf, lc, lb, gb, grid,
        n_local, gs_ptr, (f32x4*)d_out);
}

// Round 5
// 156.336 us; speedup vs baseline: 1.0237x; 1.0237x over previous
//
#include <hip/hip_runtime.h>

// GlobalFusion: scatter global rows into a dense 3D grid hash, then per local
// point gather the coarse-scale global feature row and concat with local row.
//
// R5: R3 structure + hoist per-row index resolution into a precompute kernel.
//     fuse_kernel VMEM instrs/thread: 8 -> 5 (coords+grid loads were 16x
//     redundant across the 16 lanes of a row).

#define SCALE_SHIFT 2
#define C4 16            // 64 floats = 16 float4 per input row
#define OUT4 32          // 128 floats = 32 float4 per output row

typedef float f32x4 __attribute__((ext_vector_type(4)));

__global__ void build_grid_kernel(const int* __restrict__ gcoords,
                                  int n_global,
                                  const int* __restrict__ gs_ptr,
                                  int* __restrict__ grid) {
    int i = blockIdx.x * blockDim.x + threadIdx.x;
    if (i >= n_global) return;
    int gs = *gs_ptr;
    int x = gcoords[3 * i + 0];
    int y = gcoords[3 * i + 1];
    int z = gcoords[3 * i + 2];
    // reference: grid.at[flat].max(row_index) -> atomicMax resolves duplicates
    atomicMax(&grid[(x * gs + y) * gs + z], i);
}

// Resolve each local row to its gather source row (-1 = zero fill).
__global__ void __launch_bounds__(256)
resolve_kernel(const int* __restrict__ lcoords, // n_local x 3
               const int* __restrict__ lbase,   // 3
               const int* __restrict__ gbase,   // 3
               const int* __restrict__ grid,    // gs^3
               int n_local,
               const int* __restrict__ gs_ptr,
               int* __restrict__ idx_arr)       // n_local
{
    int row = blockIdx.x * blockDim.x + threadIdx.x;
    if (row >= n_local) return;
    int gs = *gs_ptr;
    int gx = ((lcoords[3 * row + 0] + lbase[0]) >> SCALE_SHIFT) - gbase[0];
    int gy = ((lcoords[3 * row + 1] + lbase[1]) >> SCALE_SHIFT) - gbase[1];
    int gz = ((lcoords[3 * row + 2] + lbase[2]) >> SCALE_SHIFT) - gbase[2];
    bool inb = ((unsigned)gx < (unsigned)gs) &
               ((unsigned)gy < (unsigned)gs) &
               ((unsigned)gz < (unsigned)gs);
    int cx = min(max(gx, 0), gs - 1);
    int cy = min(max(gy, 0), gs - 1);
    int cz = min(max(gz, 0), gs - 1);
    int idx = grid[(cx * gs + cy) * gs + cz];
    idx_arr[row] = inb ? idx : -1;
}

__global__ void __launch_bounds__(256)
fuse_kernel(const f32x4* __restrict__ lf4,     // n_local  x 16
            const f32x4* __restrict__ gf4,     // n_global x 16
            const int* __restrict__ idx_arr,   // n_local
            int n_local,
            f32x4* __restrict__ out4)          // n_local x 32
{
    int t = blockIdx.x * blockDim.x + threadIdx.x;
    int row = t >> 4;          // 16 threads per row
    int j   = t & 15;
    if (row >= n_local) return;

    // local half: streaming copy (coalesced float4, single-use -> nt)
    f32x4 lv = __builtin_nontemporal_load(&lf4[(size_t)row * C4 + j]);
    __builtin_nontemporal_store(lv, &out4[(size_t)row * OUT4 + j]);

    // gathered half: idx load is a 16-lane broadcast (1 cacheline / row)
    int idx = idx_arr[row];
    f32x4 v = (f32x4)(0.f, 0.f, 0.f, 0.f);
    if (idx >= 0) {
        v = gf4[(size_t)idx * C4 + j];   // cached: gf reused across rows
    }
    __builtin_nontemporal_store(v, &out4[(size_t)row * OUT4 + C4 + j]);
}

extern "C" void kernel_launch(void* const* d_in, const int* in_sizes, int n_in,
                              void* d_out, int out_size, void* d_ws, size_t ws_size,
                              hipStream_t stream) {
    const float* lf = (const float*)d_in[0];
    const float* gf = (const float*)d_in[1];
    const int*   lc = (const int*)d_in[2];
    const int*   gc = (const int*)d_in[3];
    const int*   lb = (const int*)d_in[4];
    const int*   gb = (const int*)d_in[5];
    // d_in[6] = local_spatial_size (unused), d_in[7] = global_spatial_size
    const int*   gs_ptr = (const int*)d_in[7];

    int n_local  = in_sizes[0] / 64;
    int n_global = in_sizes[1] / 64;

    // workspace layout: [grid hash: 128^3 int32 = 8 MiB][idx_arr: n_local int32]
    int* grid = (int*)d_ws;
    const size_t grid_bytes = (size_t)128 * 128 * 128 * sizeof(int);
    int* idx_arr = (int*)((char*)d_ws + grid_bytes);

    hipMemsetAsync(d_ws, 0xFF, grid_bytes, stream);

    build_grid_kernel<<<(n_global + 255) / 256, 256, 0, stream>>>(
        gc, n_global, gs_ptr, grid);

    resolve_kernel<<<(n_local + 255) / 256, 256, 0, stream>>>(
        lc, lb, gb, grid, n_local, gs_ptr, idx_arr);

    long long threads = (long long)n_local * 16;
    int blocks = (int)((threads + 255) / 256);
    fuse_kernel<<<blocks, 256, 0, stream>>>(
        (const f32x4*)lf, (const f32x4*)gf, idx_arr, n_local, (f32x4*)d_out);
}

// Round 6
// 149.389 us; speedup vs baseline: 1.0713x; 1.0465x over previous
//
#include <hip/hip_runtime.h>

// GlobalFusion: scatter global rows into a dense 3D grid hash, then per local
// point gather the coarse-scale global feature row and concat with local row.
//
// R6: R3 structure exactly (16 threads/row, non-divergent, nt on streaming
//     lf-load + out-stores); single change: 1024-thread blocks (15625 blocks,
//     4x fewer dispatches, larger per-block contiguous address window).

#define SCALE_SHIFT 2
#define C4 16            // 64 floats = 16 float4 per input row
#define OUT4 32          // 128 floats = 32 float4 per output row

typedef float f32x4 __attribute__((ext_vector_type(4)));

__global__ void build_grid_kernel(const int* __restrict__ gcoords,
                                  int n_global,
                                  const int* __restrict__ gs_ptr,
                                  int* __restrict__ grid) {
    int i = blockIdx.x * blockDim.x + threadIdx.x;
    if (i >= n_global) return;
    int gs = *gs_ptr;
    int x = gcoords[3 * i + 0];
    int y = gcoords[3 * i + 1];
    int z = gcoords[3 * i + 2];
    // reference: grid.at[flat].max(row_index) -> atomicMax resolves duplicates
    atomicMax(&grid[(x * gs + y) * gs + z], i);
}

__global__ void __launch_bounds__(1024)
fuse_kernel(const f32x4* __restrict__ lf4,   // n_local  x 16
            const f32x4* __restrict__ gf4,   // n_global x 16
            const int* __restrict__ lcoords, // n_local x 3
            const int* __restrict__ lbase,   // 3
            const int* __restrict__ gbase,   // 3
            const int* __restrict__ grid,    // gs^3
            int n_local,
            const int* __restrict__ gs_ptr,
            f32x4* __restrict__ out4)        // n_local x 32
{
    int t = blockIdx.x * blockDim.x + threadIdx.x;
    int row = t >> 4;          // 16 threads per row
    int j   = t & 15;
    if (row >= n_local) return;
    int gs = *gs_ptr;

    // local half: streaming copy (coalesced float4, single-use -> nt)
    f32x4 lv = __builtin_nontemporal_load(&lf4[(size_t)row * C4 + j]);
    __builtin_nontemporal_store(lv, &out4[(size_t)row * OUT4 + j]);

    // gathered half (grid + gf reads stay cached)
    int gx = ((lcoords[3 * row + 0] + lbase[0]) >> SCALE_SHIFT) - gbase[0];
    int gy = ((lcoords[3 * row + 1] + lbase[1]) >> SCALE_SHIFT) - gbase[1];
    int gz = ((lcoords[3 * row + 2] + lbase[2]) >> SCALE_SHIFT) - gbase[2];
    bool inb = ((unsigned)gx < (unsigned)gs) &
               ((unsigned)gy < (unsigned)gs) &
               ((unsigned)gz < (unsigned)gs);
    int cx = min(max(gx, 0), gs - 1);
    int cy = min(max(gy, 0), gs - 1);
    int cz = min(max(gz, 0), gs - 1);
    int idx = grid[(cx * gs + cy) * gs + cz];

    f32x4 v = (f32x4)(0.f, 0.f, 0.f, 0.f);
    if (inb && idx >= 0) {
        v = gf4[(size_t)idx * C4 + j];
    }
    __builtin_nontemporal_store(v, &out4[(size_t)row * OUT4 + C4 + j]);
}

extern "C" void kernel_launch(void* const* d_in, const int* in_sizes, int n_in,
                              void* d_out, int out_size, void* d_ws, size_t ws_size,
                              hipStream_t stream) {
    const float* lf = (const float*)d_in[0];
    const float* gf = (const float*)d_in[1];
    const int*   lc = (const int*)d_in[2];
    const int*   gc = (const int*)d_in[3];
    const int*   lb = (const int*)d_in[4];
    const int*   gb = (const int*)d_in[5];
    // d_in[6] = local_spatial_size (unused), d_in[7] = global_spatial_size
    const int*   gs_ptr = (const int*)d_in[7];

    int n_local  = in_sizes[0] / 64;
    int n_global = in_sizes[1] / 64;

    // grid hash lives in workspace: 128^3 int32 = 8 MiB, init to -1 (0xFF)
    int* grid = (int*)d_ws;
    const size_t grid_bytes = (size_t)128 * 128 * 128 * sizeof(int);
    hipMemsetAsync(d_ws, 0xFF, grid_bytes, stream);

    build_grid_kernel<<<(n_global + 255) / 256, 256, 0, stream>>>(
        gc, n_global, gs_ptr, grid);

    long long threads = (long long)n_local * 16;
    int blocks = (int)((threads + 1023) / 1024);
    fuse_kernel<<<blocks, 1024, 0, stream>>>(
        (const f32x4*)lf, (const f32x4*)gf, lc, lb, gb, grid,
        n_local, gs_ptr, (f32x4*)d_out);
}